// Round 2
// baseline (1229.539 us; speedup 1.0000x reference)
//
#include <hip/hip_runtime.h>
#include <hip/hip_bf16.h>
#include <math.h>

// Problem constants (from reference)
#define B_      8
#define D_      64
#define HW_     (512 * 512)
#define C_      19          // NUM_CLASSES
#define K_      18          // C_ - 1 (class 0 dropped)

constexpr int THREADS   = 256;
constexpr int CHUNK     = 4096;            // pixels per block
constexpr int NCHUNK    = HW_ / CHUNK;     // 64 chunks per batch sample
constexpr int REPS      = 8;               // LDS accumulator replicas (lane&7)
constexpr int CSTRIDE   = 65;              // 64 d-slots + 1 count slot; odd => bank spread
constexpr int REPSTRIDE = C_ * CSTRIDE;    // 1235 dwords; 1235%32=19 => replicas hit distinct banks

// ---------------------------------------------------------------------------
// Kernel 1: masked per-class channel sums + counts.
// Per block: 4096 pixels of one sample. 8 d-streams per iteration (float4),
// scatter into per-lane-group LDS replicas via conflict-light ds_add_f32.
// ---------------------------------------------------------------------------
__global__ __launch_bounds__(THREADS)
void frc_accum(const float* __restrict__ feat,
               const int*   __restrict__ label,
               float*       __restrict__ gsums,   // [B][C][D] f32
               float*       __restrict__ gcnt)    // [B][C]    f32 (pixel counts)
{
    const int b    = blockIdx.y;
    const int pix0 = blockIdx.x * CHUNK;
    const int t    = threadIdx.x;

    __shared__ float    acc[REPS * REPSTRIDE];   // 39520 B
    __shared__ unsigned lab_s[CHUNK / 4];        // 4096 B (packed u8 classes)

    for (int i = t; i < REPS * REPSTRIDE; i += THREADS) acc[i] = 0.f;

    // stage labels: int32 -> packed u8 (remap 255->0, clamp for safety)
    const int4* lp = reinterpret_cast<const int4*>(label + (size_t)b * HW_ + pix0);
    for (int w = t; w < CHUNK / 4; w += THREADS) {
        int4 l = lp[w];
        unsigned c0 = (l.x == 255) ? 0u : (unsigned)l.x; if (c0 >= C_) c0 = 0;
        unsigned c1 = (l.y == 255) ? 0u : (unsigned)l.y; if (c1 >= C_) c1 = 0;
        unsigned c2 = (l.z == 255) ? 0u : (unsigned)l.z; if (c2 >= C_) c2 = 0;
        unsigned c3 = (l.w == 255) ? 0u : (unsigned)l.w; if (c3 >= C_) c3 = 0;
        lab_s[w] = c0 | (c1 << 8) | (c2 << 16) | (c3 << 24);
    }
    __syncthreads();

    float* accr = acc + (t & (REPS - 1)) * REPSTRIDE;
    const float* fb = feat + (size_t)b * D_ * HW_ + pix0;

    for (int pass = 0; pass < D_ / 8; ++pass) {            // 8 passes x 8 d-streams
        const float* fp = fb + (size_t)(pass * 8) * HW_;
        #pragma unroll 2
        for (int i = 0; i < CHUNK / (THREADS * 4); ++i) {  // 4 iters, 4 px/lane
            const int pq = i * THREADS + t;                // pixel-quad index
            const unsigned w = lab_s[pq];
            const int px = pq * 4;

            float4 v0 = *(const float4*)(fp + (size_t)0 * HW_ + px);
            float4 v1 = *(const float4*)(fp + (size_t)1 * HW_ + px);
            float4 v2 = *(const float4*)(fp + (size_t)2 * HW_ + px);
            float4 v3 = *(const float4*)(fp + (size_t)3 * HW_ + px);
            float4 v4 = *(const float4*)(fp + (size_t)4 * HW_ + px);
            float4 v5 = *(const float4*)(fp + (size_t)5 * HW_ + px);
            float4 v6 = *(const float4*)(fp + (size_t)6 * HW_ + px);
            float4 v7 = *(const float4*)(fp + (size_t)7 * HW_ + px);

            float* a0 = accr + (w & 255u)         * CSTRIDE + pass * 8;
            float* a1 = accr + ((w >> 8) & 255u)  * CSTRIDE + pass * 8;
            float* a2 = accr + ((w >> 16) & 255u) * CSTRIDE + pass * 8;
            float* a3 = accr + (w >> 24)          * CSTRIDE + pass * 8;

            atomicAdd(&a0[0], v0.x); atomicAdd(&a1[0], v0.y); atomicAdd(&a2[0], v0.z); atomicAdd(&a3[0], v0.w);
            atomicAdd(&a0[1], v1.x); atomicAdd(&a1[1], v1.y); atomicAdd(&a2[1], v1.z); atomicAdd(&a3[1], v1.w);
            atomicAdd(&a0[2], v2.x); atomicAdd(&a1[2], v2.y); atomicAdd(&a2[2], v2.z); atomicAdd(&a3[2], v2.w);
            atomicAdd(&a0[3], v3.x); atomicAdd(&a1[3], v3.y); atomicAdd(&a2[3], v3.z); atomicAdd(&a3[3], v3.w);
            atomicAdd(&a0[4], v4.x); atomicAdd(&a1[4], v4.y); atomicAdd(&a2[4], v4.z); atomicAdd(&a3[4], v4.w);
            atomicAdd(&a0[5], v5.x); atomicAdd(&a1[5], v5.y); atomicAdd(&a2[5], v5.z); atomicAdd(&a3[5], v5.w);
            atomicAdd(&a0[6], v6.x); atomicAdd(&a1[6], v6.y); atomicAdd(&a2[6], v6.z); atomicAdd(&a3[6], v6.w);
            atomicAdd(&a0[7], v7.x); atomicAdd(&a1[7], v7.y); atomicAdd(&a2[7], v7.z); atomicAdd(&a3[7], v7.w);

            if (pass == 0) {   // count each pixel once, into the class's slot 64
                atomicAdd(&a0[64], 1.0f);
                atomicAdd(&a1[64], 1.0f);
                atomicAdd(&a2[64], 1.0f);
                atomicAdd(&a3[64], 1.0f);
            }
        }
    }
    __syncthreads();

    // flush: fold 8 replicas, scatter to global
    for (int o = t; o < REPSTRIDE; o += THREADS) {
        float s = 0.f;
        #pragma unroll
        for (int r = 0; r < REPS; ++r) s += acc[r * REPSTRIDE + o];
        int c = o / CSTRIDE;
        int j = o - c * CSTRIDE;
        if (j < D_) atomicAdd(&gsums[((size_t)b * C_ + c) * D_ + j], s);
        else        atomicAdd(&gcnt[b * C_ + c], s);
    }
}

// ---------------------------------------------------------------------------
// Kernel 2: tiny epilogue -> scalar loss
// ---------------------------------------------------------------------------
__global__ __launch_bounds__(256)
void frc_finalize(const float* __restrict__ gsums,  // [B][C][D]
                  const float* __restrict__ gcnt,   // [B][C]
                  float*       __restrict__ out)
{
    __shared__ float emb[K_][D_];
    __shared__ float dots[K_][K_];
    __shared__ float sq[K_];
    __shared__ float rowloss[K_];
    const int t = threadIdx.x;

    for (int idx = t; idx < K_ * D_; idx += 256) {
        int k = idx / D_, d = idx % D_, c = k + 1;
        float e = 0.f, num = 0.f;
        #pragma unroll
        for (int b = 0; b < B_; ++b) {
            float cnt = gcnt[b * C_ + c];
            e   += gsums[((size_t)b * C_ + c) * D_ + d] / (cnt + 1e-6f);
            num += (cnt > 0.f) ? 1.f : 0.f;
        }
        emb[k][d] = e / num;
    }
    __syncthreads();

    for (int idx = t; idx < K_ * K_; idx += 256) {
        int i = idx / K_, j = idx % K_;
        float s = 0.f;
        #pragma unroll
        for (int d = 0; d < D_; ++d) s += emb[i][d] * emb[j][d];
        dots[i][j] = s;
    }
    __syncthreads();

    if (t < K_) sq[t] = dots[t][t];
    __syncthreads();

    if (t < K_) {
        float crow[K_];
        float m = -INFINITY;
        #pragma unroll
        for (int j = 0; j < K_; ++j) {
            float c = dots[t][j] / (sq[t] * sq[j]);
            crow[j] = c;
            m = fmaxf(m, c);
        }
        float s = 0.f;
        #pragma unroll
        for (int j = 0; j < K_; ++j) s += expf(crow[j] - m);
        float lse = m + logf(s);
        rowloss[t] = -(crow[t] - lse);
    }
    __syncthreads();

    if (t == 0) {
        float L = 0.f;
        #pragma unroll
        for (int i = 0; i < K_; ++i) L += rowloss[i];
        out[0] = L / (float)K_;
    }
}

// ---------------------------------------------------------------------------
extern "C" void kernel_launch(void* const* d_in, const int* in_sizes, int n_in,
                              void* d_out, int out_size, void* d_ws, size_t ws_size,
                              hipStream_t stream)
{
    const float* feat  = (const float*)d_in[0];   // [8,64,512,512] f32
    const int*   label = (const int*)d_in[1];     // [8,1,512,512] i32
    float*       out   = (float*)d_out;           // scalar

    float* gsums = (float*)d_ws;                                   // [B*C*D]
    float* gcnt  = (float*)((char*)d_ws + (size_t)B_ * C_ * D_ * sizeof(float)); // [B*C]
    size_t zero_bytes = (size_t)(B_ * C_ * D_ + B_ * C_) * sizeof(float);

    hipMemsetAsync(d_ws, 0, zero_bytes, stream);

    dim3 grid(NCHUNK, B_);   // 64 x 8 = 512 blocks
    frc_accum<<<grid, THREADS, 0, stream>>>(feat, label, gsums, gcnt);
    frc_finalize<<<1, 256, 0, stream>>>(gsums, gcnt, out);
}